// Round 1
// baseline (268.609 us; speedup 1.0000x reference)
//
#include <hip/hip_runtime.h>
#include <hip/hip_bf16.h>
#include <cstddef>

// Problem constants (match reference)
constexpr int NN = 20000;   // nodes
constexpr int NE = 320000;  // edges
constexpr int NHEAD = 4;
constexpr int HD = 512;     // H*D
constexpr int MPAD = 20096; // 314*64 padded rows for GEMM tiles
constexpr int SLOTS = 64;   // padded-CSR slots per node (Poisson(16): P(>64)~1e-20)
constexpr float NEG_SLOPE = 0.2f;

using short8 = __attribute__((ext_vector_type(8))) short;
using f32x4 = __attribute__((ext_vector_type(4))) float;

// async global->LDS, 16B per lane, LDS dest = wave-uniform base + lane*16
__device__ inline void gload16(const void* g, void* l) {
  __builtin_amdgcn_global_load_lds(
      (const __attribute__((address_space(1))) void*)g,
      (__attribute__((address_space(3))) void*)l, 16, 0, 0);
}

__device__ inline float fastrcp(float x) { return __builtin_amdgcn_rcpf(x); }

// fast ELU negative branch (see prior session): 3-inst vs ~30-inst expm1f
__device__ inline float fast_elu(float x) {
  return (x > 0.f) ? x : (__expf(x) - 1.0f);
}

// ---------------- fused prep --------------------------------------------------
// Segments: [cnt zero][feats->bf16, float4-vectorized][W1^T bf16][vcomb]
//           [wl1t/wr1t (W1 folded into al1/ar1)][partials zero]
// wl1t[d][h] = sum_{d'} W1[d, h*128+d'] * al1[h,d']   (so el1 = feats . wl1t)
// vcomb[v][k], v = 0..11: v<4 -> vl[h=v], v<8 -> vr[h=v-4], else vq[h=v-8]:
//   vl[h,k] = sum_d W2[k, h*128+d] * al2[h,d]   (el2 = h1 . vl, fp32)
constexpr int S0 = NN;                      // cnt zero
constexpr int S1 = S0 + NN * 128 / 4;       // featsb (4 elems per item)
constexpr int S2 = S1 + 512 * 128;          // W1t
constexpr int S3 = S2 + 12 * 512;           // vcomb
constexpr int S4 = S3 + 1024;               // wl1t + wr1t (128*4 each, interleaved)
constexpr int S5 = S4 + 256;                // partials zero
__global__ __launch_bounds__(256) void prep_kernel(
    const float* __restrict__ feats, const float* __restrict__ W1,
    const float* __restrict__ W2, const float* __restrict__ al1,
    const float* __restrict__ ar1, const float* __restrict__ al2,
    const float* __restrict__ ar2, const float* __restrict__ Wr,
    __hip_bfloat16* __restrict__ featsb, __hip_bfloat16* __restrict__ W1t,
    float* __restrict__ vcomb, float* __restrict__ wl1t,
    float* __restrict__ wr1t, float* __restrict__ partials,
    int* __restrict__ cnt) {
  int t = blockIdx.x * 256 + threadIdx.x;
  if (t < S0) {
    cnt[t] = 0;
  } else if (t < S1) {
    int u = (t - S0) * 4;                 // < NN*128 always (exact segment)
    float4 f = *reinterpret_cast<const float4*>(&feats[u]);
    __hip_bfloat162 o0 = __float22bfloat162_rn(make_float2(f.x, f.y));
    __hip_bfloat162 o1 = __float22bfloat162_rn(make_float2(f.z, f.w));
    uint2 pk;
    pk.x = *reinterpret_cast<unsigned int*>(&o0);
    pk.y = *reinterpret_cast<unsigned int*>(&o1);
    *reinterpret_cast<uint2*>(&featsb[u]) = pk;
  } else if (t < S2) {
    int u = t - S1;                       // W1t[col][k]
    W1t[u] = __float2bfloat16(W1[(size_t)(u & 127) * 512 + (u >> 7)]);
  } else if (t < S3) {
    int u = t - S2;                       // vcomb[v][k]
    int v = u >> 9, k = u & 511;
    int h = (v < 4) ? v : (v < 8) ? v - 4 : v - 8;
    const float* vec = (v < 4) ? (al2 + h * 128)
                     : (v < 8) ? (ar2 + h * 128) : Wr;
    const float* wrow = W2 + (size_t)k * 512 + h * 128;
    float s = 0.f;
    for (int d = 0; d < 128; ++d) s += wrow[d] * vec[d];
    vcomb[u] = s;
  } else if (t < S4) {
    int u = t - S3;                       // wl1t/wr1t[d][h]
    int d = u >> 3, rem = u & 7, h = rem >> 1, sel = rem & 1;
    const float* vec = (sel ? ar1 : al1) + h * 128;
    const float* wrow = W1 + (size_t)d * 512 + h * 128;
    float s = 0.f;
    for (int dd = 0; dd < 128; ++dd) s += wrow[dd] * vec[dd];
    (sel ? wr1t : wl1t)[d * 4 + h] = s;
  } else if (t < S5) {
    partials[t - S4] = 0.f;
  }
}

// ---------------- CSR fill + layer-1 logits ---------------------------------
// el1[n,h] = feats[n] . wl1t[:,h]  (W1 folded through al1 -> no z needed).
// Grid-stride CSR fill prologue (cnt zeroed by prep), then one wave per node.
__global__ __launch_bounds__(256) void fill_logits_kernel(
    const int* __restrict__ src, const int* __restrict__ dst,
    int* __restrict__ cnt, int* __restrict__ src_perm,
    const __hip_bfloat16* __restrict__ featsb,
    const float* __restrict__ wl1t, const float* __restrict__ wr1t,
    float* __restrict__ el1, float* __restrict__ er1) {
  int t = threadIdx.x;
  {
    int nth = gridDim.x * 256;
    int gid = blockIdx.x * 256 + t;
    for (int e = gid; e < NE; e += nth) {
      int d = dst[e];
      int p = atomicAdd(&cnt[d], 1);
      if (p < SLOTS) src_perm[d * SLOTS + p] = src[e];
    }
  }
  int wv = t >> 6, lane = t & 63;
  int n = blockIdx.x * 4 + wv;
  unsigned int uu = *reinterpret_cast<const unsigned int*>(
      &featsb[(size_t)n * 128 + 2 * lane]);
  __hip_bfloat162 ub = *reinterpret_cast<__hip_bfloat162*>(&uu);
  float2 f = __bfloat1622float2(ub);
  float4 wlA = *reinterpret_cast<const float4*>(&wl1t[lane * 8]);
  float4 wlB = *reinterpret_cast<const float4*>(&wl1t[lane * 8 + 4]);
  float4 wrA = *reinterpret_cast<const float4*>(&wr1t[lane * 8]);
  float4 wrB = *reinterpret_cast<const float4*>(&wr1t[lane * 8 + 4]);
  float p0 = f.x * wlA.x + f.y * wlB.x;
  float p1 = f.x * wlA.y + f.y * wlB.y;
  float p2 = f.x * wlA.z + f.y * wlB.z;
  float p3 = f.x * wlA.w + f.y * wlB.w;
  float p4 = f.x * wrA.x + f.y * wrB.x;
  float p5 = f.x * wrA.y + f.y * wrB.y;
  float p6 = f.x * wrA.z + f.y * wrB.z;
  float p7 = f.x * wrA.w + f.y * wrB.w;
#pragma unroll
  for (int off = 1; off < 64; off <<= 1) {
    p0 += __shfl_xor(p0, off); p1 += __shfl_xor(p1, off);
    p2 += __shfl_xor(p2, off); p3 += __shfl_xor(p3, off);
    p4 += __shfl_xor(p4, off); p5 += __shfl_xor(p5, off);
    p6 += __shfl_xor(p6, off); p7 += __shfl_xor(p7, off);
  }
  if (lane == 0) {
    *reinterpret_cast<float4*>(&el1[n * 4]) = make_float4(p0, p1, p2, p3);
    *reinterpret_cast<float4*>(&er1[n * 4]) = make_float4(p4, p5, p6, p7);
  }
}

// ---------------- layer-1 attention + FEATS aggregation ---------------------
// Key change vs prior session: aggregate feats (256 B/edge, 5.1 MB footprint,
// L2-resident) instead of z (512 B/edge, 10.3 MB) — W1 is applied AFTER the
// alpha-weighted sum (linearity).  One wave per node; phase 1 = alphas (lane =
// slot), phase 2 = 128-dim gather (lane = 2 dims), agg written bf16.
__global__ __launch_bounds__(256) void gather_kernel(
    const __hip_bfloat16* __restrict__ featsb,
    const int* __restrict__ cnt, const int* __restrict__ src_perm,
    const float* __restrict__ el, const float* __restrict__ er,
    __hip_bfloat16* __restrict__ aggb) {         // [MPAD][4*128] bf16
  __shared__ float4 alph[4][SLOTS];
  __shared__ int srcb[4][SLOTS];
  int wv = __builtin_amdgcn_readfirstlane((int)(threadIdx.x >> 6));
  int n = blockIdx.x * 4 + wv;
  int lane = threadIdx.x & 63;
  int c = min(cnt[n], SLOTS);

  // ---- phase 1: attention coefficients (lane = slot) ----
  {
    float4 er4 = *reinterpret_cast<const float4*>(&er[n * 4]);
    float a0 = 0.f, a1 = 0.f, a2 = 0.f, a3 = 0.f;
    int sv = 0;
    if (lane < c) {
      sv = src_perm[n * SLOTS + lane];
      float4 e4 = *reinterpret_cast<const float4*>(&el[sv * 4]);
      float x0 = e4.x + er4.x, x1 = e4.y + er4.y;
      float x2 = e4.z + er4.z, x3 = e4.w + er4.w;
      x0 = (x0 > 0.f) ? x0 : NEG_SLOPE * x0;
      x1 = (x1 > 0.f) ? x1 : NEG_SLOPE * x1;
      x2 = (x2 > 0.f) ? x2 : NEG_SLOPE * x2;
      x3 = (x3 > 0.f) ? x3 : NEG_SLOPE * x3;
      a0 = __expf(x0); a1 = __expf(x1); a2 = __expf(x2); a3 = __expf(x3);
    }
    float s0 = a0, s1 = a1, s2 = a2, s3 = a3;
#pragma unroll
    for (int off = 1; off < 64; off <<= 1) {
      s0 += __shfl_xor(s0, off);
      s1 += __shfl_xor(s1, off);
      s2 += __shfl_xor(s2, off);
      s3 += __shfl_xor(s3, off);
    }
    float i0 = fastrcp(fmaxf(s0, 1e-9f));
    float i1 = fastrcp(fmaxf(s1, 1e-9f));
    float i2 = fastrcp(fmaxf(s2, 1e-9f));
    float i3 = fastrcp(fmaxf(s3, 1e-9f));
    alph[wv][lane] = make_float4(a0 * i0, a1 * i1, a2 * i2, a3 * i3);
    srcb[wv][lane] = sv;   // same-wave producer/consumer, no barrier
  }

  // ---- phase 2: feats gather (lane = 2 dims), 4-deep unroll ----
  float acc[4][2] = {};

#define EB(IDX)                                                                \
  {                                                                            \
    float4 a4 = alph[wv][(IDX)];                                               \
    int s = srcb[wv][(IDX)];                                                   \
    unsigned int uu = *reinterpret_cast<const unsigned int*>(                  \
        &featsb[(size_t)s * 128 + 2 * lane]);                                  \
    __hip_bfloat162 ub = *reinterpret_cast<__hip_bfloat162*>(&uu);             \
    float2 f = __bfloat1622float2(ub);                                         \
    acc[0][0] += a4.x * f.x; acc[0][1] += a4.x * f.y;                          \
    acc[1][0] += a4.y * f.x; acc[1][1] += a4.y * f.y;                          \
    acc[2][0] += a4.z * f.x; acc[2][1] += a4.z * f.y;                          \
    acc[3][0] += a4.w * f.x; acc[3][1] += a4.w * f.y;                          \
  }

  int i = 0;
  for (; i + 3 < c; i += 4) {
    EB(i) EB(i + 1) EB(i + 2) EB(i + 3)
  }
  for (; i < c; ++i) EB(i)
#undef EB

  size_t obase = (size_t)n * HD + 2 * lane;
#pragma unroll
  for (int h = 0; h < 4; ++h) {
    __hip_bfloat162 o = __float22bfloat162_rn(make_float2(acc[h][0], acc[h][1]));
    *reinterpret_cast<unsigned int*>(&aggb[obase + h * 128]) =
        *reinterpret_cast<unsigned int*>(&o);
  }
}

// ---------------- h1 GEMM + fused 12-dot epilogue ---------------------------
// h1[n, h*128+d'] = elu(agg[n,h,:] @ W1[:, h*128+d'] + b1); h1 never stored —
// el2/er2/q2 = h1 . vcomb computed in the epilogue.  64-row tiles, 4 waves
// (2 rows x 2 cols of 32x64), head loop reuses acc; per-(node,vv) partials
// reduced by 4-level butterfly, lane mrow==vv keeps its vv across heads,
// col-halves combined through LDS (single writer per node -> plain stores).
__global__ __launch_bounds__(256) void h1_gemm_kernel(
    const __hip_bfloat16* __restrict__ A,   // aggb [MPAD][512] bf16
    const __hip_bfloat16* __restrict__ Bt,  // W1t  [512][128] bf16
    const float* __restrict__ b1,           // [512]
    const float* __restrict__ vcomb,        // [12][512]
    float* __restrict__ el2, float* __restrict__ er2,
    float* __restrict__ q2) {
  __shared__ short As[64 * 32];
  __shared__ short Bs[128 * 32];
  __shared__ float vc[12 * 512];
  __shared__ float redbuf[64][12][2];
  int t = threadIdx.x;
  for (int idx = t; idx < 12 * 512; idx += 256) vc[idx] = vcomb[idx];
  int lane = t & 63, wave = t >> 6;
  int rowBase = blockIdx.x * 64;
  int woffr = (wave & 1) * 32;
  int woffc = (wave >> 1) * 64;
  int ch = wave >> 1;
  int mrow = lane & 15, quad = lane >> 4;
  float keep[8] = {0.f, 0.f, 0.f, 0.f, 0.f, 0.f, 0.f, 0.f};
  __syncthreads();  // vc ready

  for (int head = 0; head < 4; ++head) {
    f32x4 acc[2][4];
#pragma unroll
    for (int i = 0; i < 2; ++i)
#pragma unroll
      for (int j = 0; j < 4; ++j) acc[i][j] = (f32x4){0.f, 0.f, 0.f, 0.f};

    for (int k0 = 0; k0 < 128; k0 += 32) {
      {
        int f = wave * 64 + lane;            // 256 A-chunks
        int r = f >> 2, kc = f & 3;
        gload16(A + (size_t)(rowBase + r) * HD + head * 128 + k0 + kc * 8,
                As + wave * 512);
      }
#pragma unroll
      for (int p = 0; p < 2; ++p) {          // 512 B-chunks
        int f = p * 256 + wave * 64 + lane;
        int r = f >> 2, kc = f & 3;
        gload16(Bt + (size_t)(head * 128 + r) * 128 + k0 + kc * 8,
                Bs + p * 2048 + wave * 512);
      }
      __syncthreads();
      short8 af[2], bfr[4];
#pragma unroll
      for (int i = 0; i < 2; ++i)
        af[i] = *(const short8*)&As[(woffr + i * 16 + mrow) * 32 + quad * 8];
#pragma unroll
      for (int j = 0; j < 4; ++j)
        bfr[j] = *(const short8*)&Bs[(woffc + j * 16 + mrow) * 32 + quad * 8];
#pragma unroll
      for (int i = 0; i < 2; ++i)
#pragma unroll
        for (int j = 0; j < 4; ++j)
          acc[i][j] = __builtin_amdgcn_mfma_f32_16x16x32_bf16(af[i], bfr[j],
                                                              acc[i][j], 0, 0, 0);
      __syncthreads();
    }

    // epilogue: elu(acc + b1) then partial dots with vcomb (this head's k-slice)
    float b1g[4];
#pragma unroll
    for (int j = 0; j < 4; ++j)
      b1g[j] = b1[head * 128 + woffc + j * 16 + mrow];
#pragma unroll
    for (int i = 0; i < 2; ++i)
#pragma unroll
      for (int j = 0; j < 4; ++j)
#pragma unroll
        for (int r = 0; r < 4; ++r)
          acc[i][j][r] = fast_elu(acc[i][j][r] + b1g[j]);

#pragma unroll
    for (int vv = 0; vv < 12; ++vv) {
      float vc4[4];
#pragma unroll
      for (int j = 0; j < 4; ++j)
        vc4[j] = vc[vv * 512 + head * 128 + woffc + j * 16 + mrow];
#pragma unroll
      for (int i = 0; i < 2; ++i)
#pragma unroll
        for (int r = 0; r < 4; ++r) {
          float p = acc[i][0][r] * vc4[0] + acc[i][1][r] * vc4[1] +
                    acc[i][2][r] * vc4[2] + acc[i][3][r] * vc4[3];
          p += __shfl_xor(p, 1);
          p += __shfl_xor(p, 2);
          p += __shfl_xor(p, 4);
          p += __shfl_xor(p, 8);
          if (mrow == vv) keep[i * 4 + r] += p;
        }
    }
  }

  if (mrow < 12) {
#pragma unroll
    for (int i = 0; i < 2; ++i)
#pragma unroll
      for (int r = 0; r < 4; ++r)
        redbuf[woffr + i * 16 + quad * 4 + r][mrow][ch] = keep[i * 4 + r];
  }
  __syncthreads();
  for (int idx = t; idx < 64 * 12; idx += 256) {
    int node = idx / 12;
    int vv = idx - node * 12;
    float s = redbuf[node][vv][0] + redbuf[node][vv][1];
    int n = rowBase + node;
    if (n < NN) {
      float* dp = (vv < 4) ? el2 : (vv < 8) ? er2 : q2;
      dp[(size_t)n * 4 + (vv & 3)] = s;
    }
  }
}

// ---------------- layer-2 attention + readout dot ---------------------------
// Unchanged from prior session (validated): one wave per dst node, alpha
// butterfly, dot with q[src], block partial -> 256-slot atomics.
__global__ __launch_bounds__(256) void attn_q_kernel(
    const int* __restrict__ src_perm,
    const int* __restrict__ cnt,
    const float* __restrict__ el,
    const float* __restrict__ er,
    const float* __restrict__ q,            // [NN][4]
    float* __restrict__ partials) {         // [256]
  __shared__ float blk[4];
  int wv = __builtin_amdgcn_readfirstlane((int)(threadIdx.x >> 6));
  int n = blockIdx.x * 4 + wv;
  int lane = threadIdx.x & 63;
  int c = min(cnt[n], SLOTS);
  float4 er4 = *reinterpret_cast<const float4*>(&er[n * 4]);
  float a0 = 0.f, a1 = 0.f, a2 = 0.f, a3 = 0.f;
  int s = 0;
  if (lane < c) {
    s = src_perm[n * SLOTS + lane];
    float4 e4 = *reinterpret_cast<const float4*>(&el[s * 4]);
    float x0 = e4.x + er4.x, x1 = e4.y + er4.y;
    float x2 = e4.z + er4.z, x3 = e4.w + er4.w;
    x0 = (x0 > 0.f) ? x0 : NEG_SLOPE * x0;
    x1 = (x1 > 0.f) ? x1 : NEG_SLOPE * x1;
    x2 = (x2 > 0.f) ? x2 : NEG_SLOPE * x2;
    x3 = (x3 > 0.f) ? x3 : NEG_SLOPE * x3;
    a0 = __expf(x0); a1 = __expf(x1); a2 = __expf(x2); a3 = __expf(x3);
  }
  float s0 = a0, s1 = a1, s2 = a2, s3 = a3;
#pragma unroll
  for (int off = 1; off < 64; off <<= 1) {
    s0 += __shfl_xor(s0, off);
    s1 += __shfl_xor(s1, off);
    s2 += __shfl_xor(s2, off);
    s3 += __shfl_xor(s3, off);
  }
  float p = 0.f;
  if (lane < c) {
    float4 q4 = *reinterpret_cast<const float4*>(&q[s * 4]);
    p = (a0 * fastrcp(fmaxf(s0, 1e-9f))) * q4.x +
        (a1 * fastrcp(fmaxf(s1, 1e-9f))) * q4.y +
        (a2 * fastrcp(fmaxf(s2, 1e-9f))) * q4.z +
        (a3 * fastrcp(fmaxf(s3, 1e-9f))) * q4.w;
  }
#pragma unroll
  for (int off = 32; off > 0; off >>= 1) p += __shfl_down(p, off);
  if (lane == 0) blk[wv] = p;
  __syncthreads();
  if (threadIdx.x == 0) {
    atomicAdd(&partials[blockIdx.x & 255], blk[0] + blk[1] + blk[2] + blk[3]);
  }
}

// ---------------- final: out = 0.25*(sum partials + NN*b2.Wr_rep) + NN*br ----
__global__ __launch_bounds__(512) void final_kernel(
    const float* __restrict__ partials, const float* __restrict__ b2,
    const float* __restrict__ Wr, const float* __restrict__ br,
    float* __restrict__ out) {
  __shared__ float tmp[512];
  int t = threadIdx.x;
  float sum = (t < 256) ? partials[t] : 0.f;
  sum += (float)NN * b2[t] * Wr[t & 127];
  tmp[t] = sum;
  __syncthreads();
  for (int off = 256; off > 0; off >>= 1) {
    if (t < off) tmp[t] += tmp[t + off];
    __syncthreads();
  }
  if (t == 0) out[0] = 0.25f * tmp[0] + (float)NN * br[0];
}

// ---------------- launch ----------------
extern "C" void kernel_launch(void* const* d_in, const int* in_sizes, int n_in,
                              void* d_out, int out_size, void* d_ws, size_t ws_size,
                              hipStream_t stream) {
  const float* feats = (const float*)d_in[0];
  const int* src = (const int*)d_in[1];
  const int* dst = (const int*)d_in[2];
  const float* W1 = (const float*)d_in[3];
  const float* al1 = (const float*)d_in[4];
  const float* ar1 = (const float*)d_in[5];
  const float* b1 = (const float*)d_in[6];
  const float* W2 = (const float*)d_in[7];
  const float* al2 = (const float*)d_in[8];
  const float* ar2 = (const float*)d_in[9];
  const float* b2 = (const float*)d_in[10];
  const float* Wr = (const float*)d_in[11];
  const float* br = (const float*)d_in[12];
  float* out = (float*)d_out;

  // workspace layout (~33 MB); all section sizes multiples of 16 B
  __hip_bfloat16* featsb = (__hip_bfloat16*)d_ws;               // NN*128 bf16
  __hip_bfloat16* aggb = featsb + (size_t)NN * 128;             // MPAD*512 bf16
  __hip_bfloat16* W1t = aggb + (size_t)MPAD * HD;               // 512*128 bf16
  float* vcomb = (float*)(W1t + 512 * 128);                     // 12*512 f32
  float* wl1t = vcomb + 12 * 512;                               // 128*4 f32
  float* wr1t = wl1t + 512;                                     // 128*4 f32
  float* el1 = wr1t + 512;                                      // NN*4
  float* er1 = el1 + (size_t)NN * NHEAD;                        // NN*4
  float* el2 = er1 + (size_t)NN * NHEAD;                        // NN*4
  float* er2 = el2 + (size_t)NN * NHEAD;                        // NN*4
  float* q2 = er2 + (size_t)NN * NHEAD;                         // NN*4
  float* partials = q2 + (size_t)NN * NHEAD;                    // 256
  int* cnt = (int*)(partials + 256);                            // NN
  int* src_perm = cnt + NN;                                     // NN*SLOTS

  // prep: cnt zero + feats->bf16 + W1^T + vcomb + wl1t/wr1t + partials zero
  prep_kernel<<<(S5 + 255) / 256, 256, 0, stream>>>(
      feats, W1, W2, al1, ar1, al2, ar2, Wr, featsb, W1t, vcomb, wl1t, wr1t,
      partials, cnt);

  // CSR fill + layer-1 logits (W1 folded — no z GEMM)
  fill_logits_kernel<<<NN / 4, 256, 0, stream>>>(
      src, dst, cnt, src_perm, featsb, wl1t, wr1t, el1, er1);

  // layer-1 attn + FEATS aggregation (256 B/edge, L2-resident footprint)
  gather_kernel<<<NN / 4, 256, 0, stream>>>(featsb, cnt, src_perm, el1, er1,
                                            aggb);

  // agg @ W1 -> h1 (in-register) -> el2/er2/q2 (12 folded dots, h1 never stored)
  h1_gemm_kernel<<<MPAD / 64, 256, 0, stream>>>(aggb, W1t, b1, vcomb, el2,
                                                er2, q2);

  // layer-2 attention + readout dot, then tiny final reduce
  attn_q_kernel<<<NN / 4, 256, 0, stream>>>(src_perm, cnt, el2, er2, q2,
                                            partials);
  final_kernel<<<1, 512, 0, stream>>>(partials, b2, Wr, br, out);
}

// Round 2
// 214.137 us; speedup vs baseline: 1.2544x; 1.2544x over previous
//
#include <hip/hip_runtime.h>
#include <hip/hip_bf16.h>
#include <cstddef>

// Problem constants (match reference)
constexpr int NN = 20000;   // nodes
constexpr int NE = 320000;  // edges
constexpr int NHEAD = 4;
constexpr int HD = 512;     // H*D
constexpr int MPAD = 20096; // 314*64 padded rows for GEMM tiles
constexpr int SLOTS = 64;   // padded-CSR slots per node (Poisson(16): P(>64)~1e-20)
constexpr float NEG_SLOPE = 0.2f;

using short8 = __attribute__((ext_vector_type(8))) short;
using f32x4 = __attribute__((ext_vector_type(4))) float;

// async global->LDS, 16B per lane, LDS dest = wave-uniform base + lane*16
__device__ inline void gload16(const void* g, void* l) {
  __builtin_amdgcn_global_load_lds(
      (const __attribute__((address_space(1))) void*)g,
      (__attribute__((address_space(3))) void*)l, 16, 0, 0);
}

__device__ inline float fastrcp(float x) { return __builtin_amdgcn_rcpf(x); }

// fast ELU negative branch: 3-inst vs ~30-inst expm1f
__device__ inline float fast_elu(float x) {
  return (x > 0.f) ? x : (__expf(x) - 1.0f);
}

// ---------------- fused prep --------------------------------------------------
// Segments: [cnt zero][feats->bf16, float4-vectorized][W1^T bf16][vcomb]
//           [wl1t/wr1t (W1 folded into al1/ar1)][el2/er2/q2 zero][partials zero]
// wl1t[d][h] = sum_{d'} W1[d, h*128+d'] * al1[h,d']   (so el1 = feats . wl1t)
// vcomb[v][k], v = 0..11: v<4 -> vl[h=v], v<8 -> vr[h=v-4], else vq[h=v-8]:
//   vl[h,k] = sum_d W2[k, h*128+d] * al2[h,d]   (el2 = h1 . vl, fp32)
constexpr int S0 = NN;                      // cnt zero
constexpr int S1 = S0 + NN * 128 / 4;       // featsb (4 elems per item)
constexpr int S2 = S1 + 512 * 128;          // W1t
constexpr int S3 = S2 + 12 * 512;           // vcomb
constexpr int S4 = S3 + 1024;               // wl1t + wr1t (128*4 each, interleaved)
constexpr int S5 = S4 + 60000;              // el2/er2/q2 zero (3*NN*4 floats, x4)
constexpr int S6 = S5 + 256;                // partials zero
__global__ __launch_bounds__(256) void prep_kernel(
    const float* __restrict__ feats, const float* __restrict__ W1,
    const float* __restrict__ W2, const float* __restrict__ al1,
    const float* __restrict__ ar1, const float* __restrict__ al2,
    const float* __restrict__ ar2, const float* __restrict__ Wr,
    __hip_bfloat16* __restrict__ featsb, __hip_bfloat16* __restrict__ W1t,
    float* __restrict__ vcomb, float* __restrict__ wl1t,
    float* __restrict__ wr1t, float* __restrict__ zero3,
    float* __restrict__ partials, int* __restrict__ cnt) {
  int t = blockIdx.x * 256 + threadIdx.x;
  if (t < S0) {
    cnt[t] = 0;
  } else if (t < S1) {
    int u = (t - S0) * 4;                 // < NN*128 always (exact segment)
    float4 f = *reinterpret_cast<const float4*>(&feats[u]);
    __hip_bfloat162 o0 = __float22bfloat162_rn(make_float2(f.x, f.y));
    __hip_bfloat162 o1 = __float22bfloat162_rn(make_float2(f.z, f.w));
    uint2 pk;
    pk.x = *reinterpret_cast<unsigned int*>(&o0);
    pk.y = *reinterpret_cast<unsigned int*>(&o1);
    *reinterpret_cast<uint2*>(&featsb[u]) = pk;
  } else if (t < S2) {
    int u = t - S1;                       // W1t[col][k]
    W1t[u] = __float2bfloat16(W1[(size_t)(u & 127) * 512 + (u >> 7)]);
  } else if (t < S3) {
    int u = t - S2;                       // vcomb[v][k]
    int v = u >> 9, k = u & 511;
    int h = (v < 4) ? v : (v < 8) ? v - 4 : v - 8;
    const float* vec = (v < 4) ? (al2 + h * 128)
                     : (v < 8) ? (ar2 + h * 128) : Wr;
    const float* wrow = W2 + (size_t)k * 512 + h * 128;
    float s = 0.f;
    for (int d = 0; d < 128; ++d) s += wrow[d] * vec[d];
    vcomb[u] = s;
  } else if (t < S4) {
    int u = t - S3;                       // wl1t/wr1t[d][h]
    int d = u >> 3, rem = u & 7, h = rem >> 1, sel = rem & 1;
    const float* vec = (sel ? ar1 : al1) + h * 128;
    const float* wrow = W1 + (size_t)d * 512 + h * 128;
    float s = 0.f;
    for (int dd = 0; dd < 128; ++dd) s += wrow[dd] * vec[dd];
    (sel ? wr1t : wl1t)[d * 4 + h] = s;
  } else if (t < S5) {
    int u = (t - S4) * 4;                 // el2/er2/q2 contiguous zero
    *reinterpret_cast<float4*>(&zero3[u]) = make_float4(0.f, 0.f, 0.f, 0.f);
  } else if (t < S6) {
    partials[t - S5] = 0.f;
  }
}

// ---------------- CSR fill + layer-1 logits ---------------------------------
// el1[n,h] = feats[n] . wl1t[:,h]  (W1 folded through al1 -> no z needed).
// Grid-stride CSR fill prologue (cnt zeroed by prep), then one wave per node.
__global__ __launch_bounds__(256) void fill_logits_kernel(
    const int* __restrict__ src, const int* __restrict__ dst,
    int* __restrict__ cnt, int* __restrict__ src_perm,
    const __hip_bfloat16* __restrict__ featsb,
    const float* __restrict__ wl1t, const float* __restrict__ wr1t,
    float* __restrict__ el1, float* __restrict__ er1) {
  int t = threadIdx.x;
  {
    int nth = gridDim.x * 256;
    int gid = blockIdx.x * 256 + t;
    for (int e = gid; e < NE; e += nth) {
      int d = dst[e];
      int p = atomicAdd(&cnt[d], 1);
      if (p < SLOTS) src_perm[d * SLOTS + p] = src[e];
    }
  }
  int wv = t >> 6, lane = t & 63;
  int n = blockIdx.x * 4 + wv;
  unsigned int uu = *reinterpret_cast<const unsigned int*>(
      &featsb[(size_t)n * 128 + 2 * lane]);
  __hip_bfloat162 ub = *reinterpret_cast<__hip_bfloat162*>(&uu);
  float2 f = __bfloat1622float2(ub);
  float4 wlA = *reinterpret_cast<const float4*>(&wl1t[lane * 8]);
  float4 wlB = *reinterpret_cast<const float4*>(&wl1t[lane * 8 + 4]);
  float4 wrA = *reinterpret_cast<const float4*>(&wr1t[lane * 8]);
  float4 wrB = *reinterpret_cast<const float4*>(&wr1t[lane * 8 + 4]);
  float p0 = f.x * wlA.x + f.y * wlB.x;
  float p1 = f.x * wlA.y + f.y * wlB.y;
  float p2 = f.x * wlA.z + f.y * wlB.z;
  float p3 = f.x * wlA.w + f.y * wlB.w;
  float p4 = f.x * wrA.x + f.y * wrB.x;
  float p5 = f.x * wrA.y + f.y * wrB.y;
  float p6 = f.x * wrA.z + f.y * wrB.z;
  float p7 = f.x * wrA.w + f.y * wrB.w;
#pragma unroll
  for (int off = 1; off < 64; off <<= 1) {
    p0 += __shfl_xor(p0, off); p1 += __shfl_xor(p1, off);
    p2 += __shfl_xor(p2, off); p3 += __shfl_xor(p3, off);
    p4 += __shfl_xor(p4, off); p5 += __shfl_xor(p5, off);
    p6 += __shfl_xor(p6, off); p7 += __shfl_xor(p7, off);
  }
  if (lane == 0) {
    *reinterpret_cast<float4*>(&el1[n * 4]) = make_float4(p0, p1, p2, p3);
    *reinterpret_cast<float4*>(&er1[n * 4]) = make_float4(p4, p5, p6, p7);
  }
}

// ---------------- layer-1 attention + FEATS aggregation ---------------------
// Aggregate feats (256 B/edge, 5.1 MB footprint) — W1 applied AFTER the
// alpha-weighted sum (linearity).  One wave per node.
__global__ __launch_bounds__(256) void gather_kernel(
    const __hip_bfloat16* __restrict__ featsb,
    const int* __restrict__ cnt, const int* __restrict__ src_perm,
    const float* __restrict__ el, const float* __restrict__ er,
    __hip_bfloat16* __restrict__ aggb) {         // [MPAD][4*128] bf16
  __shared__ float4 alph[4][SLOTS];
  __shared__ int srcb[4][SLOTS];
  int wv = __builtin_amdgcn_readfirstlane((int)(threadIdx.x >> 6));
  int n = blockIdx.x * 4 + wv;
  int lane = threadIdx.x & 63;
  int c = min(cnt[n], SLOTS);

  // ---- phase 1: attention coefficients (lane = slot) ----
  {
    float4 er4 = *reinterpret_cast<const float4*>(&er[n * 4]);
    float a0 = 0.f, a1 = 0.f, a2 = 0.f, a3 = 0.f;
    int sv = 0;
    if (lane < c) {
      sv = src_perm[n * SLOTS + lane];
      float4 e4 = *reinterpret_cast<const float4*>(&el[sv * 4]);
      float x0 = e4.x + er4.x, x1 = e4.y + er4.y;
      float x2 = e4.z + er4.z, x3 = e4.w + er4.w;
      x0 = (x0 > 0.f) ? x0 : NEG_SLOPE * x0;
      x1 = (x1 > 0.f) ? x1 : NEG_SLOPE * x1;
      x2 = (x2 > 0.f) ? x2 : NEG_SLOPE * x2;
      x3 = (x3 > 0.f) ? x3 : NEG_SLOPE * x3;
      a0 = __expf(x0); a1 = __expf(x1); a2 = __expf(x2); a3 = __expf(x3);
    }
    float s0 = a0, s1 = a1, s2 = a2, s3 = a3;
#pragma unroll
    for (int off = 1; off < 64; off <<= 1) {
      s0 += __shfl_xor(s0, off);
      s1 += __shfl_xor(s1, off);
      s2 += __shfl_xor(s2, off);
      s3 += __shfl_xor(s3, off);
    }
    float i0 = fastrcp(fmaxf(s0, 1e-9f));
    float i1 = fastrcp(fmaxf(s1, 1e-9f));
    float i2 = fastrcp(fmaxf(s2, 1e-9f));
    float i3 = fastrcp(fmaxf(s3, 1e-9f));
    alph[wv][lane] = make_float4(a0 * i0, a1 * i1, a2 * i2, a3 * i3);
    srcb[wv][lane] = sv;   // same-wave producer/consumer, no barrier
  }

  // ---- phase 2: feats gather (lane = 2 dims), 4-deep unroll ----
  float acc[4][2] = {};

#define EB(IDX)                                                                \
  {                                                                            \
    float4 a4 = alph[wv][(IDX)];                                               \
    int s = srcb[wv][(IDX)];                                                   \
    unsigned int uu = *reinterpret_cast<const unsigned int*>(                  \
        &featsb[(size_t)s * 128 + 2 * lane]);                                  \
    __hip_bfloat162 ub = *reinterpret_cast<__hip_bfloat162*>(&uu);             \
    float2 f = __bfloat1622float2(ub);                                         \
    acc[0][0] += a4.x * f.x; acc[0][1] += a4.x * f.y;                          \
    acc[1][0] += a4.y * f.x; acc[1][1] += a4.y * f.y;                          \
    acc[2][0] += a4.z * f.x; acc[2][1] += a4.z * f.y;                          \
    acc[3][0] += a4.w * f.x; acc[3][1] += a4.w * f.y;                          \
  }

  int i = 0;
  for (; i + 3 < c; i += 4) {
    EB(i) EB(i + 1) EB(i + 2) EB(i + 3)
  }
  for (; i < c; ++i) EB(i)
#undef EB

  size_t obase = (size_t)n * HD + 2 * lane;
#pragma unroll
  for (int h = 0; h < 4; ++h) {
    __hip_bfloat162 o = __float22bfloat162_rn(make_float2(acc[h][0], acc[h][1]));
    *reinterpret_cast<unsigned int*>(&aggb[obase + h * 128]) =
        *reinterpret_cast<unsigned int*>(&o);
  }
}

// ---------------- h1 GEMM + fused 12-dot epilogue ---------------------------
// Latency-tolerant restructure (R1 was 16 serial load-barrier stages at 1.2
// blocks/CU -> 139us at 0.7% MfmaUtil):
//  * head -> gridDim.y: (314, 4) = 1256 blocks, per-head partials atomicAdd
//    into zero-initialized el2/er2/q2.
//  * ONE load phase: whole A tile (64x128) + B head-slice (128x128) + vc
//    staged in a single gload16 burst, one barrier, then 32 MFMAs from LDS.
//  * LDS 57 KB -> 2 blocks/CU; next block's loads overlap this one's MFMAs.
//  * XOR swizzle slot^=(row&7) BOTH sides (pre-swizzled global source +
//    swizzled ds_read) kills the 8-way bank conflict (rule #21).
__global__ __launch_bounds__(256) void h1_gemm_kernel(
    const __hip_bfloat16* __restrict__ A,   // aggb [MPAD][512] bf16
    const __hip_bfloat16* __restrict__ Bt,  // W1t  [512][128] bf16
    const float* __restrict__ b1,           // [512]
    const float* __restrict__ vcomb,        // [12][512]
    float* __restrict__ el2, float* __restrict__ er2,
    float* __restrict__ q2) {
  __shared__ short As[64 * 128];            // 16 KB
  __shared__ short Bs[128 * 128];           // 32 KB
  __shared__ float vc[12 * 128];            // 6 KB (this head's slice)
  __shared__ float redbuf[64][12];          // 3 KB
  int t = threadIdx.x;
  int lane = t & 63, wave = t >> 6;
  int rowBase = blockIdx.x * 64;
  int head = blockIdx.y;
  int wr = wave & 1, wc = wave >> 1;
  int woffr = wr * 32, woffc = wc * 64;
  int mrow = lane & 15, quad = lane >> 4;

  // ---- single staging phase (source swizzled, LDS linear) ----
#pragma unroll
  for (int p = 0; p < 4; ++p) {             // A: 64 rows x 16 slots
    int fbase = p * 256 + wave * 64;        // wave-uniform LDS base
    int f = fbase + lane;
    int row = f >> 4, slot = f & 15;
    int ss = slot ^ (row & 7);
    gload16(A + (size_t)(rowBase + row) * HD + head * 128 + ss * 8,
            As + fbase * 8);
  }
#pragma unroll
  for (int p = 0; p < 8; ++p) {             // B: 128 rows x 16 slots
    int fbase = p * 256 + wave * 64;
    int f = fbase + lane;
    int row = f >> 4, slot = f & 15;
    int ss = slot ^ (row & 7);
    gload16(Bt + (size_t)(head * 128 + row) * 128 + ss * 8,
            Bs + fbase * 8);
  }
  for (int idx = t; idx < 12 * 128; idx += 256)
    vc[idx] = vcomb[(idx >> 7) * 512 + head * 128 + (idx & 127)];
  __syncthreads();

  // ---- 32 MFMAs from LDS, no further barriers ----
  f32x4 acc[2][4];
#pragma unroll
  for (int i = 0; i < 2; ++i)
#pragma unroll
    for (int j = 0; j < 4; ++j) acc[i][j] = (f32x4){0.f, 0.f, 0.f, 0.f};

#pragma unroll
  for (int step = 0; step < 4; ++step) {
    short8 af[2], bfr[4];
#pragma unroll
    for (int i = 0; i < 2; ++i) {
      int row = woffr + i * 16 + mrow;
      af[i] = *(const short8*)&As[row * 128 +
                                  (((step << 2) + quad) ^ (row & 7)) * 8];
    }
#pragma unroll
    for (int j = 0; j < 4; ++j) {
      int rb = woffc + j * 16 + mrow;
      bfr[j] = *(const short8*)&Bs[rb * 128 +
                                   (((step << 2) + quad) ^ (rb & 7)) * 8];
    }
#pragma unroll
    for (int i = 0; i < 2; ++i)
#pragma unroll
      for (int j = 0; j < 4; ++j)
        acc[i][j] = __builtin_amdgcn_mfma_f32_16x16x32_bf16(af[i], bfr[j],
                                                            acc[i][j], 0, 0, 0);
  }

  // ---- epilogue: elu(acc + b1), 12 vcomb dots, butterfly, atomic combine ----
  float b1g[4];
#pragma unroll
  for (int j = 0; j < 4; ++j)
    b1g[j] = b1[head * 128 + woffc + j * 16 + mrow];
#pragma unroll
  for (int i = 0; i < 2; ++i)
#pragma unroll
    for (int j = 0; j < 4; ++j)
#pragma unroll
      for (int r = 0; r < 4; ++r)
        acc[i][j][r] = fast_elu(acc[i][j][r] + b1g[j]);

  float keep[8] = {0.f, 0.f, 0.f, 0.f, 0.f, 0.f, 0.f, 0.f};
#pragma unroll
  for (int vv = 0; vv < 12; ++vv) {
    float vc4[4];
#pragma unroll
    for (int j = 0; j < 4; ++j)
      vc4[j] = vc[vv * 128 + woffc + j * 16 + mrow];
#pragma unroll
    for (int i = 0; i < 2; ++i)
#pragma unroll
      for (int r = 0; r < 4; ++r) {
        float p = acc[i][0][r] * vc4[0] + acc[i][1][r] * vc4[1] +
                  acc[i][2][r] * vc4[2] + acc[i][3][r] * vc4[3];
        p += __shfl_xor(p, 1);
        p += __shfl_xor(p, 2);
        p += __shfl_xor(p, 4);
        p += __shfl_xor(p, 8);
        if (mrow == vv) keep[i * 4 + r] = p;
      }
  }
  if (wc == 1 && mrow < 12) {
#pragma unroll
    for (int i = 0; i < 2; ++i)
#pragma unroll
      for (int r = 0; r < 4; ++r)
        redbuf[woffr + i * 16 + quad * 4 + r][mrow] = keep[i * 4 + r];
  }
  __syncthreads();
  if (wc == 0 && mrow < 12) {
    float* dp = (mrow < 4) ? el2 : (mrow < 8) ? er2 : q2;
    int h4 = mrow & 3;
#pragma unroll
    for (int i = 0; i < 2; ++i)
#pragma unroll
      for (int r = 0; r < 4; ++r) {
        int node = woffr + i * 16 + quad * 4 + r;
        int n = rowBase + node;
        if (n < NN)
          atomicAdd(&dp[(size_t)n * 4 + h4], keep[i * 4 + r] + redbuf[node][mrow]);
      }
  }
}

// ---------------- layer-2 attention + readout dot ---------------------------
__global__ __launch_bounds__(256) void attn_q_kernel(
    const int* __restrict__ src_perm,
    const int* __restrict__ cnt,
    const float* __restrict__ el,
    const float* __restrict__ er,
    const float* __restrict__ q,            // [NN][4]
    float* __restrict__ partials) {         // [256]
  __shared__ float blk[4];
  int wv = __builtin_amdgcn_readfirstlane((int)(threadIdx.x >> 6));
  int n = blockIdx.x * 4 + wv;
  int lane = threadIdx.x & 63;
  int c = min(cnt[n], SLOTS);
  float4 er4 = *reinterpret_cast<const float4*>(&er[n * 4]);
  float a0 = 0.f, a1 = 0.f, a2 = 0.f, a3 = 0.f;
  int s = 0;
  if (lane < c) {
    s = src_perm[n * SLOTS + lane];
    float4 e4 = *reinterpret_cast<const float4*>(&el[s * 4]);
    float x0 = e4.x + er4.x, x1 = e4.y + er4.y;
    float x2 = e4.z + er4.z, x3 = e4.w + er4.w;
    x0 = (x0 > 0.f) ? x0 : NEG_SLOPE * x0;
    x1 = (x1 > 0.f) ? x1 : NEG_SLOPE * x1;
    x2 = (x2 > 0.f) ? x2 : NEG_SLOPE * x2;
    x3 = (x3 > 0.f) ? x3 : NEG_SLOPE * x3;
    a0 = __expf(x0); a1 = __expf(x1); a2 = __expf(x2); a3 = __expf(x3);
  }
  float s0 = a0, s1 = a1, s2 = a2, s3 = a3;
#pragma unroll
  for (int off = 1; off < 64; off <<= 1) {
    s0 += __shfl_xor(s0, off);
    s1 += __shfl_xor(s1, off);
    s2 += __shfl_xor(s2, off);
    s3 += __shfl_xor(s3, off);
  }
  float p = 0.f;
  if (lane < c) {
    float4 q4 = *reinterpret_cast<const float4*>(&q[s * 4]);
    p = (a0 * fastrcp(fmaxf(s0, 1e-9f))) * q4.x +
        (a1 * fastrcp(fmaxf(s1, 1e-9f))) * q4.y +
        (a2 * fastrcp(fmaxf(s2, 1e-9f))) * q4.z +
        (a3 * fastrcp(fmaxf(s3, 1e-9f))) * q4.w;
  }
#pragma unroll
  for (int off = 32; off > 0; off >>= 1) p += __shfl_down(p, off);
  if (lane == 0) blk[wv] = p;
  __syncthreads();
  if (threadIdx.x == 0) {
    atomicAdd(&partials[blockIdx.x & 255], blk[0] + blk[1] + blk[2] + blk[3]);
  }
}

// ---------------- final: out = 0.25*(sum partials + NN*b2.Wr_rep) + NN*br ----
__global__ __launch_bounds__(512) void final_kernel(
    const float* __restrict__ partials, const float* __restrict__ b2,
    const float* __restrict__ Wr, const float* __restrict__ br,
    float* __restrict__ out) {
  __shared__ float tmp[512];
  int t = threadIdx.x;
  float sum = (t < 256) ? partials[t] : 0.f;
  sum += (float)NN * b2[t] * Wr[t & 127];
  tmp[t] = sum;
  __syncthreads();
  for (int off = 256; off > 0; off >>= 1) {
    if (t < off) tmp[t] += tmp[t + off];
    __syncthreads();
  }
  if (t == 0) out[0] = 0.25f * tmp[0] + (float)NN * br[0];
}

// ---------------- launch ----------------
extern "C" void kernel_launch(void* const* d_in, const int* in_sizes, int n_in,
                              void* d_out, int out_size, void* d_ws, size_t ws_size,
                              hipStream_t stream) {
  const float* feats = (const float*)d_in[0];
  const int* src = (const int*)d_in[1];
  const int* dst = (const int*)d_in[2];
  const float* W1 = (const float*)d_in[3];
  const float* al1 = (const float*)d_in[4];
  const float* ar1 = (const float*)d_in[5];
  const float* b1 = (const float*)d_in[6];
  const float* W2 = (const float*)d_in[7];
  const float* al2 = (const float*)d_in[8];
  const float* ar2 = (const float*)d_in[9];
  const float* b2 = (const float*)d_in[10];
  const float* Wr = (const float*)d_in[11];
  const float* br = (const float*)d_in[12];
  float* out = (float*)d_out;

  // workspace layout (~33 MB); all section sizes multiples of 16 B
  __hip_bfloat16* featsb = (__hip_bfloat16*)d_ws;               // NN*128 bf16
  __hip_bfloat16* aggb = featsb + (size_t)NN * 128;             // MPAD*512 bf16
  __hip_bfloat16* W1t = aggb + (size_t)MPAD * HD;               // 512*128 bf16
  float* vcomb = (float*)(W1t + 512 * 128);                     // 12*512 f32
  float* wl1t = vcomb + 12 * 512;                               // 128*4 f32
  float* wr1t = wl1t + 512;                                     // 128*4 f32
  float* el1 = wr1t + 512;                                      // NN*4
  float* er1 = el1 + (size_t)NN * NHEAD;                        // NN*4
  float* el2 = er1 + (size_t)NN * NHEAD;                        // NN*4
  float* er2 = el2 + (size_t)NN * NHEAD;                        // NN*4
  float* q2 = er2 + (size_t)NN * NHEAD;                         // NN*4
  float* partials = q2 + (size_t)NN * NHEAD;                    // 256
  int* cnt = (int*)(partials + 256);                            // NN
  int* src_perm = cnt + NN;                                     // NN*SLOTS

  // prep: cnt zero + feats->bf16 + W1^T + vcomb + wl1t/wr1t + out-zeros
  prep_kernel<<<(S6 + 255) / 256, 256, 0, stream>>>(
      feats, W1, W2, al1, ar1, al2, ar2, Wr, featsb, W1t, vcomb, wl1t, wr1t,
      el2, partials, cnt);

  // CSR fill + layer-1 logits (W1 folded — no z GEMM)
  fill_logits_kernel<<<NN / 4, 256, 0, stream>>>(
      src, dst, cnt, src_perm, featsb, wl1t, wr1t, el1, er1);

  // layer-1 attn + FEATS aggregation (256 B/edge)
  gather_kernel<<<NN / 4, 256, 0, stream>>>(featsb, cnt, src_perm, el1, er1,
                                            aggb);

  // agg @ W1 -> h1 (in-register) -> el2/er2/q2 partials (atomic over heads)
  dim3 h1grid(MPAD / 64, NHEAD);
  h1_gemm_kernel<<<h1grid, 256, 0, stream>>>(aggb, W1t, b1, vcomb, el2,
                                             er2, q2);

  // layer-2 attention + readout dot, then tiny final reduce
  attn_q_kernel<<<NN / 4, 256, 0, stream>>>(src_perm, cnt, el2, er2, q2,
                                            partials);
  final_kernel<<<1, 512, 0, stream>>>(partials, b2, Wr, br, out);
}

// Round 3
// 164.743 us; speedup vs baseline: 1.6305x; 1.2998x over previous
//
#include <hip/hip_runtime.h>
#include <hip/hip_bf16.h>
#include <cstddef>

// Problem constants (match reference)
constexpr int NN = 20000;   // nodes
constexpr int NE = 320000;  // edges
constexpr int NHEAD = 4;
constexpr int HD = 512;     // H*D
constexpr int MPAD = 20096; // 314*64 padded rows for GEMM tiles
constexpr int SLOTS = 64;   // padded-CSR slots per node (Poisson(16): P(>64)~1e-20)
constexpr float NEG_SLOPE = 0.2f;

using short8 = __attribute__((ext_vector_type(8))) short;
using f32x4 = __attribute__((ext_vector_type(4))) float;

// async global->LDS, 16B per lane, LDS dest = wave-uniform base + lane*16
__device__ inline void gload16(const void* g, void* l) {
  __builtin_amdgcn_global_load_lds(
      (const __attribute__((address_space(1))) void*)g,
      (__attribute__((address_space(3))) void*)l, 16, 0, 0);
}

__device__ inline float fastrcp(float x) { return __builtin_amdgcn_rcpf(x); }

// fast ELU negative branch: 3-inst vs ~30-inst expm1f
__device__ inline float fast_elu(float x) {
  return (x > 0.f) ? x : (__expf(x) - 1.0f);
}

// ---------------- fused prep --------------------------------------------------
// Segments: [cnt zero][feats->bf16, float4-vectorized][W1^T bf16]
//           [vcombh bf16, swizzled][wl1t/wr1t][el2/er2/q2 zero][partials zero]
// wl1t[d][h] = sum_{d'} W1[d, h*128+d'] * al1[h,d']   (so el1 = feats . wl1t)
// vcombh[head][m][k'] bf16, m = 0..15 (12 used, 4 zero rows for MFMA pad):
//   m<4 -> vl[h=m], m<8 -> vr[h=m-4], m<12 -> vq[h=m-8];
//   value(m, k=head*128+kk) = sum_d W2[k, h*128+d] * vec[d].
//   Stored with 16B-slot XOR swizzle: slot' = slot ^ (m&7) so the h1 kernel's
//   ds_read_b128 A-fragments are bank-conflict-free.
constexpr int S0 = NN;                      // cnt zero
constexpr int S1 = S0 + NN * 128 / 4;       // featsb (4 elems per item)
constexpr int S2 = S1 + 512 * 128;          // W1t
constexpr int S3 = S2 + 4 * 16 * 128;       // vcombh (8192)
constexpr int S4 = S3 + 1024;               // wl1t + wr1t (128*4 each, interleaved)
constexpr int S5 = S4 + 60000;              // el2/er2/q2 zero (3*NN*4 floats, x4)
constexpr int S6 = S5 + 256;                // partials zero
__global__ __launch_bounds__(256) void prep_kernel(
    const float* __restrict__ feats, const float* __restrict__ W1,
    const float* __restrict__ W2, const float* __restrict__ al1,
    const float* __restrict__ ar1, const float* __restrict__ al2,
    const float* __restrict__ ar2, const float* __restrict__ Wr,
    __hip_bfloat16* __restrict__ featsb, __hip_bfloat16* __restrict__ W1t,
    __hip_bfloat16* __restrict__ vcombh, float* __restrict__ wl1t,
    float* __restrict__ wr1t, float* __restrict__ zero3,
    float* __restrict__ partials, int* __restrict__ cnt) {
  int t = blockIdx.x * 256 + threadIdx.x;
  if (t < S0) {
    cnt[t] = 0;
  } else if (t < S1) {
    int u = (t - S0) * 4;                 // < NN*128 always (exact segment)
    float4 f = *reinterpret_cast<const float4*>(&feats[u]);
    __hip_bfloat162 o0 = __float22bfloat162_rn(make_float2(f.x, f.y));
    __hip_bfloat162 o1 = __float22bfloat162_rn(make_float2(f.z, f.w));
    uint2 pk;
    pk.x = *reinterpret_cast<unsigned int*>(&o0);
    pk.y = *reinterpret_cast<unsigned int*>(&o1);
    *reinterpret_cast<uint2*>(&featsb[u]) = pk;
  } else if (t < S2) {
    int u = t - S1;                       // W1t[col][k]
    W1t[u] = __float2bfloat16(W1[(size_t)(u & 127) * 512 + (u >> 7)]);
  } else if (t < S3) {
    int u = t - S2;                       // vcombh[head][m][kk]
    int head = u >> 11, rem = u & 2047;
    int m = rem >> 7, kk = rem & 127;
    float s = 0.f;
    if (m < 12) {
      int h = m & 3;
      const float* vec = (m < 4) ? (al2 + h * 128)
                       : (m < 8) ? (ar2 + h * 128) : Wr;
      const float* wrow = W2 + (size_t)(head * 128 + kk) * 512 + h * 128;
      for (int d = 0; d < 128; ++d) s += wrow[d] * vec[d];
    }
    int slot = kk >> 3, e = kk & 7;
    int sl = slot ^ (m & 7);
    vcombh[head * 2048 + m * 128 + sl * 8 + e] = __float2bfloat16(s);
  } else if (t < S4) {
    int u = t - S3;                       // wl1t/wr1t[d][h]
    int d = u >> 3, rem = u & 7, h = rem >> 1, sel = rem & 1;
    const float* vec = (sel ? ar1 : al1) + h * 128;
    const float* wrow = W1 + (size_t)d * 512 + h * 128;
    float s = 0.f;
    for (int dd = 0; dd < 128; ++dd) s += wrow[dd] * vec[dd];
    (sel ? wr1t : wl1t)[d * 4 + h] = s;
  } else if (t < S5) {
    int u = (t - S4) * 4;                 // el2/er2/q2 contiguous zero
    *reinterpret_cast<float4*>(&zero3[u]) = make_float4(0.f, 0.f, 0.f, 0.f);
  } else if (t < S6) {
    partials[t - S5] = 0.f;
  }
}

// ---------------- CSR fill + layer-1 logits ---------------------------------
// el1[n,h] = feats[n] . wl1t[:,h]  (W1 folded through al1 -> no z needed).
// Grid-stride CSR fill prologue (cnt zeroed by prep), then one wave per node.
__global__ __launch_bounds__(256) void fill_logits_kernel(
    const int* __restrict__ src, const int* __restrict__ dst,
    int* __restrict__ cnt, int* __restrict__ src_perm,
    const __hip_bfloat16* __restrict__ featsb,
    const float* __restrict__ wl1t, const float* __restrict__ wr1t,
    float* __restrict__ el1, float* __restrict__ er1) {
  int t = threadIdx.x;
  {
    int nth = gridDim.x * 256;
    int gid = blockIdx.x * 256 + t;
    for (int e = gid; e < NE; e += nth) {
      int d = dst[e];
      int p = atomicAdd(&cnt[d], 1);
      if (p < SLOTS) src_perm[d * SLOTS + p] = src[e];
    }
  }
  int wv = t >> 6, lane = t & 63;
  int n = blockIdx.x * 4 + wv;
  unsigned int uu = *reinterpret_cast<const unsigned int*>(
      &featsb[(size_t)n * 128 + 2 * lane]);
  __hip_bfloat162 ub = *reinterpret_cast<__hip_bfloat162*>(&uu);
  float2 f = __bfloat1622float2(ub);
  float4 wlA = *reinterpret_cast<const float4*>(&wl1t[lane * 8]);
  float4 wlB = *reinterpret_cast<const float4*>(&wl1t[lane * 8 + 4]);
  float4 wrA = *reinterpret_cast<const float4*>(&wr1t[lane * 8]);
  float4 wrB = *reinterpret_cast<const float4*>(&wr1t[lane * 8 + 4]);
  float p0 = f.x * wlA.x + f.y * wlB.x;
  float p1 = f.x * wlA.y + f.y * wlB.y;
  float p2 = f.x * wlA.z + f.y * wlB.z;
  float p3 = f.x * wlA.w + f.y * wlB.w;
  float p4 = f.x * wrA.x + f.y * wrB.x;
  float p5 = f.x * wrA.y + f.y * wrB.y;
  float p6 = f.x * wrA.z + f.y * wrB.z;
  float p7 = f.x * wrA.w + f.y * wrB.w;
#pragma unroll
  for (int off = 1; off < 64; off <<= 1) {
    p0 += __shfl_xor(p0, off); p1 += __shfl_xor(p1, off);
    p2 += __shfl_xor(p2, off); p3 += __shfl_xor(p3, off);
    p4 += __shfl_xor(p4, off); p5 += __shfl_xor(p5, off);
    p6 += __shfl_xor(p6, off); p7 += __shfl_xor(p7, off);
  }
  if (lane == 0) {
    *reinterpret_cast<float4*>(&el1[n * 4]) = make_float4(p0, p1, p2, p3);
    *reinterpret_cast<float4*>(&er1[n * 4]) = make_float4(p4, p5, p6, p7);
  }
}

// ---------------- layer-1 attention + FEATS aggregation ---------------------
// Aggregate feats (256 B/edge, 5.1 MB footprint) — W1 applied AFTER the
// alpha-weighted sum (linearity).  One wave per node.
__global__ __launch_bounds__(256) void gather_kernel(
    const __hip_bfloat16* __restrict__ featsb,
    const int* __restrict__ cnt, const int* __restrict__ src_perm,
    const float* __restrict__ el, const float* __restrict__ er,
    __hip_bfloat16* __restrict__ aggb) {         // [MPAD][4*128] bf16
  __shared__ float4 alph[4][SLOTS];
  __shared__ int srcb[4][SLOTS];
  int wv = __builtin_amdgcn_readfirstlane((int)(threadIdx.x >> 6));
  int n = blockIdx.x * 4 + wv;
  int lane = threadIdx.x & 63;
  int c = min(cnt[n], SLOTS);

  // ---- phase 1: attention coefficients (lane = slot) ----
  {
    float4 er4 = *reinterpret_cast<const float4*>(&er[n * 4]);
    float a0 = 0.f, a1 = 0.f, a2 = 0.f, a3 = 0.f;
    int sv = 0;
    if (lane < c) {
      sv = src_perm[n * SLOTS + lane];
      float4 e4 = *reinterpret_cast<const float4*>(&el[sv * 4]);
      float x0 = e4.x + er4.x, x1 = e4.y + er4.y;
      float x2 = e4.z + er4.z, x3 = e4.w + er4.w;
      x0 = (x0 > 0.f) ? x0 : NEG_SLOPE * x0;
      x1 = (x1 > 0.f) ? x1 : NEG_SLOPE * x1;
      x2 = (x2 > 0.f) ? x2 : NEG_SLOPE * x2;
      x3 = (x3 > 0.f) ? x3 : NEG_SLOPE * x3;
      a0 = __expf(x0); a1 = __expf(x1); a2 = __expf(x2); a3 = __expf(x3);
    }
    float s0 = a0, s1 = a1, s2 = a2, s3 = a3;
#pragma unroll
    for (int off = 1; off < 64; off <<= 1) {
      s0 += __shfl_xor(s0, off);
      s1 += __shfl_xor(s1, off);
      s2 += __shfl_xor(s2, off);
      s3 += __shfl_xor(s3, off);
    }
    float i0 = fastrcp(fmaxf(s0, 1e-9f));
    float i1 = fastrcp(fmaxf(s1, 1e-9f));
    float i2 = fastrcp(fmaxf(s2, 1e-9f));
    float i3 = fastrcp(fmaxf(s3, 1e-9f));
    alph[wv][lane] = make_float4(a0 * i0, a1 * i1, a2 * i2, a3 * i3);
    srcb[wv][lane] = sv;   // same-wave producer/consumer, no barrier
  }

  // ---- phase 2: feats gather (lane = 2 dims), 4-deep unroll ----
  float acc[4][2] = {};

#define EB(IDX)                                                                \
  {                                                                            \
    float4 a4 = alph[wv][(IDX)];                                               \
    int s = srcb[wv][(IDX)];                                                   \
    unsigned int uu = *reinterpret_cast<const unsigned int*>(                  \
        &featsb[(size_t)s * 128 + 2 * lane]);                                  \
    __hip_bfloat162 ub = *reinterpret_cast<__hip_bfloat162*>(&uu);             \
    float2 f = __bfloat1622float2(ub);                                         \
    acc[0][0] += a4.x * f.x; acc[0][1] += a4.x * f.y;                          \
    acc[1][0] += a4.y * f.x; acc[1][1] += a4.y * f.y;                          \
    acc[2][0] += a4.z * f.x; acc[2][1] += a4.z * f.y;                          \
    acc[3][0] += a4.w * f.x; acc[3][1] += a4.w * f.y;                          \
  }

  int i = 0;
  for (; i + 3 < c; i += 4) {
    EB(i) EB(i + 1) EB(i + 2) EB(i + 3)
  }
  for (; i < c; ++i) EB(i)
#undef EB

  size_t obase = (size_t)n * HD + 2 * lane;
#pragma unroll
  for (int h = 0; h < 4; ++h) {
    __hip_bfloat162 o = __float22bfloat162_rn(make_float2(acc[h][0], acc[h][1]));
    *reinterpret_cast<unsigned int*>(&aggb[obase + h * 128]) =
        *reinterpret_cast<unsigned int*>(&o);
  }
}

// ---------------- h1 GEMM + MFMA 12-dot epilogue ----------------------------
// R2's 70us was the epilogue: 384 CHAINED __shfl_xor per thread (dep-chain
// latency, un-hideable; SQ_LDS_BANK_CONFLICT ~480K came from those DS ops,
// not the GEMM reads).  This version has ZERO shuffles:
//  * First GEMM with SWAPPED operands: D[col][node] (A = W1t tile, B = agg
//    tile) so lane&15 = node — h1 lands B-fragment-ready for a second MFMA.
//  * elu(acc+b1) -> bf16 -> swizzled LDS write (wave-local rows, H1s overlays
//    As: each wave fully reads its 16 As rows before rewriting them; DS ops
//    of one wave complete in order, no barrier needed).
//  * Second GEMM: D2[vv][node] = vcombh[16x128] . h1[128xnodes] — 4 MFMAs per
//    wave replace all 12 butterfly dots; direct atomicAdd per (node, vv<12).
// LDS 52 KB -> 3 blocks/CU for latency overlap.
__global__ __launch_bounds__(256) void h1_gemm_kernel(
    const __hip_bfloat16* __restrict__ A,    // aggb [MPAD][512] bf16
    const __hip_bfloat16* __restrict__ Bt,   // W1t  [512][128] bf16
    const __hip_bfloat16* __restrict__ vcombh, // [4][16][128] bf16 pre-swizzled
    const float* __restrict__ b1,            // [512]
    float* __restrict__ el2, float* __restrict__ er2,
    float* __restrict__ q2) {
  __shared__ short AsH[64 * 128];           // 16 KB: agg tile, then h1 tile
  __shared__ short Bs[128 * 128];           // 32 KB: W1t head-slice
  __shared__ short Vc[16 * 128];            // 4 KB: vcombh head-slice
  int t = threadIdx.x;
  int lane = t & 63, wave = t >> 6;
  int rowBase = blockIdx.x * 64;
  int head = blockIdx.y;
  int nloc = lane & 15;                     // free-dim index within fragment
  int quad = lane >> 4;

  // ---- single staging phase (source pre-swizzled, LDS linear) ----
#pragma unroll
  for (int p = 0; p < 4; ++p) {             // A: 64 rows x 16 slots
    int fbase = p * 256 + wave * 64;        // wave-uniform LDS base
    int f = fbase + lane;
    int row = f >> 4, slot = f & 15;
    int ss = slot ^ (row & 7);
    gload16(A + (size_t)(rowBase + row) * HD + head * 128 + ss * 8,
            AsH + fbase * 8);
  }
#pragma unroll
  for (int p = 0; p < 8; ++p) {             // B: 128 rows x 16 slots
    int fbase = p * 256 + wave * 64;
    int f = fbase + lane;
    int row = f >> 4, slot = f & 15;
    int ss = slot ^ (row & 7);
    gload16(Bt + (size_t)(head * 128 + row) * 128 + ss * 8,
            Bs + fbase * 8);
  }
  {
    int fbase = wave * 64;                  // Vc: already swizzled in global
    gload16(vcombh + head * 2048 + (size_t)(fbase + lane) * 8,
            Vc + fbase * 8);
  }
  __syncthreads();

  // ---- first GEMM: D[col][node], wave owns 16 nodes x all 128 cols ----
  f32x4 acc[8];
#pragma unroll
  for (int i = 0; i < 8; ++i) acc[i] = (f32x4){0.f, 0.f, 0.f, 0.f};
#pragma unroll
  for (int c = 0; c < 4; ++c) {
    int arow = wave * 16 + nloc;            // agg node row (B-operand)
    short8 bfr = *(const short8*)&AsH[arow * 128 +
                                      (((c << 2) + quad) ^ (arow & 7)) * 8];
#pragma unroll
    for (int i = 0; i < 8; ++i) {
      int brow = i * 16 + nloc;             // W1t col row (A-operand)
      short8 af = *(const short8*)&Bs[brow * 128 +
                                      (((c << 2) + quad) ^ (brow & 7)) * 8];
      acc[i] = __builtin_amdgcn_mfma_f32_16x16x32_bf16(af, bfr, acc[i], 0, 0, 0);
    }
  }

  // ---- elu(acc + b1) -> bf16 -> H1s (overlay on AsH, wave-local rows) ----
  int node = wave * 16 + nloc;
#pragma unroll
  for (int i = 0; i < 8; ++i) {
    float4 b4 = *reinterpret_cast<const float4*>(
        &b1[head * 128 + i * 16 + quad * 4]);
    float e0 = fast_elu(acc[i][0] + b4.x);
    float e1 = fast_elu(acc[i][1] + b4.y);
    float e2 = fast_elu(acc[i][2] + b4.z);
    float e3 = fast_elu(acc[i][3] + b4.w);
    __hip_bfloat162 p0 = __float22bfloat162_rn(make_float2(e0, e1));
    __hip_bfloat162 p1 = __float22bfloat162_rn(make_float2(e2, e3));
    uint2 pk;
    pk.x = *reinterpret_cast<unsigned int*>(&p0);
    pk.y = *reinterpret_cast<unsigned int*>(&p1);
    int slot = i * 2 + (quad >> 1);         // 16B slot of col i*16+quad*4
    int sub = quad & 1;                     // low/high 8B within slot
    int sl = slot ^ (node & 7);
    *reinterpret_cast<uint2*>(&AsH[node * 128 + sl * 8 + sub * 4]) = pk;
  }

  // ---- second GEMM: D2[vv][node] = Vc[16x128] . h1[128x16] ----
  f32x4 acc2 = (f32x4){0.f, 0.f, 0.f, 0.f};
#pragma unroll
  for (int c = 0; c < 4; ++c) {
    short8 a2 = *(const short8*)&Vc[nloc * 128 +
                                    (((c << 2) + quad) ^ (nloc & 7)) * 8];
    short8 b2 = *(const short8*)&AsH[node * 128 +
                                     (((c << 2) + quad) ^ (node & 7)) * 8];
    acc2 = __builtin_amdgcn_mfma_f32_16x16x32_bf16(a2, b2, acc2, 0, 0, 0);
  }

  // D2 layout: vv = quad*4 + r, node = lane&15 (this wave's 16 nodes)
  int gn = rowBase + node;
  if (gn < NN && quad < 3) {
    float* dp = (quad == 0) ? el2 : (quad == 1) ? er2 : q2;
#pragma unroll
    for (int r = 0; r < 4; ++r)
      atomicAdd(&dp[(size_t)gn * 4 + r], acc2[r]);
  }
}

// ---------------- layer-2 attention + readout dot ---------------------------
__global__ __launch_bounds__(256) void attn_q_kernel(
    const int* __restrict__ src_perm,
    const int* __restrict__ cnt,
    const float* __restrict__ el,
    const float* __restrict__ er,
    const float* __restrict__ q,            // [NN][4]
    float* __restrict__ partials) {         // [256]
  __shared__ float blk[4];
  int wv = __builtin_amdgcn_readfirstlane((int)(threadIdx.x >> 6));
  int n = blockIdx.x * 4 + wv;
  int lane = threadIdx.x & 63;
  int c = min(cnt[n], SLOTS);
  float4 er4 = *reinterpret_cast<const float4*>(&er[n * 4]);
  float a0 = 0.f, a1 = 0.f, a2 = 0.f, a3 = 0.f;
  int s = 0;
  if (lane < c) {
    s = src_perm[n * SLOTS + lane];
    float4 e4 = *reinterpret_cast<const float4*>(&el[s * 4]);
    float x0 = e4.x + er4.x, x1 = e4.y + er4.y;
    float x2 = e4.z + er4.z, x3 = e4.w + er4.w;
    x0 = (x0 > 0.f) ? x0 : NEG_SLOPE * x0;
    x1 = (x1 > 0.f) ? x1 : NEG_SLOPE * x1;
    x2 = (x2 > 0.f) ? x2 : NEG_SLOPE * x2;
    x3 = (x3 > 0.f) ? x3 : NEG_SLOPE * x3;
    a0 = __expf(x0); a1 = __expf(x1); a2 = __expf(x2); a3 = __expf(x3);
  }
  float s0 = a0, s1 = a1, s2 = a2, s3 = a3;
#pragma unroll
  for (int off = 1; off < 64; off <<= 1) {
    s0 += __shfl_xor(s0, off);
    s1 += __shfl_xor(s1, off);
    s2 += __shfl_xor(s2, off);
    s3 += __shfl_xor(s3, off);
  }
  float p = 0.f;
  if (lane < c) {
    float4 q4 = *reinterpret_cast<const float4*>(&q[s * 4]);
    p = (a0 * fastrcp(fmaxf(s0, 1e-9f))) * q4.x +
        (a1 * fastrcp(fmaxf(s1, 1e-9f))) * q4.y +
        (a2 * fastrcp(fmaxf(s2, 1e-9f))) * q4.z +
        (a3 * fastrcp(fmaxf(s3, 1e-9f))) * q4.w;
  }
#pragma unroll
  for (int off = 32; off > 0; off >>= 1) p += __shfl_down(p, off);
  if (lane == 0) blk[wv] = p;
  __syncthreads();
  if (threadIdx.x == 0) {
    atomicAdd(&partials[blockIdx.x & 255], blk[0] + blk[1] + blk[2] + blk[3]);
  }
}

// ---------------- final: out = 0.25*(sum partials + NN*b2.Wr_rep) + NN*br ----
__global__ __launch_bounds__(512) void final_kernel(
    const float* __restrict__ partials, const float* __restrict__ b2,
    const float* __restrict__ Wr, const float* __restrict__ br,
    float* __restrict__ out) {
  __shared__ float tmp[512];
  int t = threadIdx.x;
  float sum = (t < 256) ? partials[t] : 0.f;
  sum += (float)NN * b2[t] * Wr[t & 127];
  tmp[t] = sum;
  __syncthreads();
  for (int off = 256; off > 0; off >>= 1) {
    if (t < off) tmp[t] += tmp[t + off];
    __syncthreads();
  }
  if (t == 0) out[0] = 0.25f * tmp[0] + (float)NN * br[0];
}

// ---------------- launch ----------------
extern "C" void kernel_launch(void* const* d_in, const int* in_sizes, int n_in,
                              void* d_out, int out_size, void* d_ws, size_t ws_size,
                              hipStream_t stream) {
  const float* feats = (const float*)d_in[0];
  const int* src = (const int*)d_in[1];
  const int* dst = (const int*)d_in[2];
  const float* W1 = (const float*)d_in[3];
  const float* al1 = (const float*)d_in[4];
  const float* ar1 = (const float*)d_in[5];
  const float* b1 = (const float*)d_in[6];
  const float* W2 = (const float*)d_in[7];
  const float* al2 = (const float*)d_in[8];
  const float* ar2 = (const float*)d_in[9];
  const float* b2 = (const float*)d_in[10];
  const float* Wr = (const float*)d_in[11];
  const float* br = (const float*)d_in[12];
  float* out = (float*)d_out;

  // workspace layout (~33 MB); all section sizes multiples of 16 B
  __hip_bfloat16* featsb = (__hip_bfloat16*)d_ws;               // NN*128 bf16
  __hip_bfloat16* aggb = featsb + (size_t)NN * 128;             // MPAD*512 bf16
  __hip_bfloat16* W1t = aggb + (size_t)MPAD * HD;               // 512*128 bf16
  __hip_bfloat16* vcombh = W1t + 512 * 128;                     // 4*16*128 bf16
  float* wl1t = (float*)(vcombh + 4 * 16 * 128);                // 128*4 f32
  float* wr1t = wl1t + 512;                                     // 128*4 f32
  float* el1 = wr1t + 512;                                      // NN*4
  float* er1 = el1 + (size_t)NN * NHEAD;                        // NN*4
  float* el2 = er1 + (size_t)NN * NHEAD;                        // NN*4
  float* er2 = el2 + (size_t)NN * NHEAD;                        // NN*4
  float* q2 = er2 + (size_t)NN * NHEAD;                         // NN*4
  float* partials = q2 + (size_t)NN * NHEAD;                    // 256
  int* cnt = (int*)(partials + 256);                            // NN
  int* src_perm = cnt + NN;                                     // NN*SLOTS

  // prep: cnt zero + feats->bf16 + W1^T + vcombh + wl1t/wr1t + out-zeros
  prep_kernel<<<(S6 + 255) / 256, 256, 0, stream>>>(
      feats, W1, W2, al1, ar1, al2, ar2, Wr, featsb, W1t, vcombh, wl1t, wr1t,
      el2, partials, cnt);

  // CSR fill + layer-1 logits (W1 folded — no z GEMM)
  fill_logits_kernel<<<NN / 4, 256, 0, stream>>>(
      src, dst, cnt, src_perm, featsb, wl1t, wr1t, el1, er1);

  // layer-1 attn + FEATS aggregation (256 B/edge)
  gather_kernel<<<NN / 4, 256, 0, stream>>>(featsb, cnt, src_perm, el1, er1,
                                            aggb);

  // agg @ W1 -> h1 (in-register/LDS) -> el2/er2/q2 partials (atomic over heads)
  dim3 h1grid(MPAD / 64, NHEAD);
  h1_gemm_kernel<<<h1grid, 256, 0, stream>>>(aggb, W1t, vcombh, b1, el2,
                                             er2, q2);

  // layer-2 attention + readout dot, then tiny final reduce
  attn_q_kernel<<<NN / 4, 256, 0, stream>>>(src_perm, cnt, el2, er2, q2,
                                            partials);
  final_kernel<<<1, 512, 0, stream>>>(partials, b2, Wr, br, out);
}